// Round 1
// baseline (248.599 us; speedup 1.0000x reference)
//
#include <hip/hip_runtime.h>
#include <hip/hip_bf16.h>

#define NN 2048
#define FF 64
#define NH 8
#define BDIM 4
#define BH 32        // BDIM*NH

typedef __attribute__((ext_vector_type(8))) short short8;
typedef __attribute__((ext_vector_type(4))) float floatx4;
typedef __attribute__((ext_vector_type(4))) unsigned uint4v;

__device__ __forceinline__ float LDIN(const void* p, size_t i, int b16) {
    return b16 ? __bfloat162float(((const __hip_bfloat16*)p)[i]) : ((const float*)p)[i];
}
__device__ __forceinline__ unsigned packhi(float f0, float f1) {
    return __builtin_amdgcn_perm(__float_as_uint(f1), __float_as_uint(f0), 0x07060302);
}
__device__ __forceinline__ float hitrunc(float x) {
    return __uint_as_float(__float_as_uint(x) & 0xFFFF0000u);
}
// XOR-swizzled LDS index (stride 64 shorts, 8-short groups). col must be 4-aligned.
__device__ __forceinline__ int SWZ(int row, int col) {
    return row * 64 + ((((col >> 3) ^ (row & 7)) << 3) | (col & 7));
}
__device__ __forceinline__ float fast_tanh(float v) {
    float ex = __expf(2.0f * v);
    return 1.0f - 2.0f * __builtin_amdgcn_rcpf(ex + 1.0f);
}
__device__ __forceinline__ int sniff_b16(const void* h) {
    unsigned word = ((const unsigned*)h)[threadIdx.x & 63];
    unsigned lowexp = (word >> 7) & 0xFFu;
    bool plaus = (lowexp >= 96u && lowexp <= 159u);
    unsigned long long m = __ballot(plaus);
    return (__popcll(m) >= 48) ? 1 : 0;
}
// orderable u64 key: ascending sort => d DESCENDING; low 32 bits = original index
__device__ __forceinline__ unsigned long long packKey(float d, int j) {
    unsigned u = __float_as_uint(d);
    u = (u & 0x80000000u) ? ~u : (u | 0x80000000u);
    return ((unsigned long long)(~u) << 32) | (unsigned)j;
}
__device__ __forceinline__ float unpackD(unsigned long long kk) {
    unsigned u = ~(unsigned)(kk >> 32);
    u = (u & 0x80000000u) ? (u & 0x7FFFFFFFu) : ~u;
    return __uint_as_float(u);
}

// ---- Kernel 0: one-time w fragmentization (unchanged) -----------------------
__global__ __launch_bounds__(256) void k_prep(
    const void* __restrict__ h, const void* __restrict__ w,
    ushort* __restrict__ wF, int* __restrict__ flagOut)
{
    const int hd = blockIdx.x, t = threadIdx.x;
    __shared__ int sb16;
    if (t < 64) {
        int f = sniff_b16(h);
        if (t == 0) { sb16 = f; if (hd == 0) flagOut[0] = f; }
    }
    __syncthreads();
    const int b16 = sb16;

#pragma unroll
    for (int g = 0; g < 2; ++g) {
        int gi = t * 2 + g;
        int ml = gi & 15, q = (gi >> 4) & 3, kc = (gi >> 6) & 1, nt = (gi >> 7) & 3;
        int n = nt * 16 + ml, kb = kc * 32 + q * 8;
        size_t off = (size_t)hd * 4096 + ((nt * 2 + kc) * 4 + q) * 128 + ml * 8;
        if (b16) {
            const ushort* wp = (const ushort*)w + (size_t)hd * FF * FF;
            ushort hi[8];
#pragma unroll
            for (int j = 0; j < 8; ++j) hi[j] = wp[(kb + j) * FF + n];
            *(uint4v*)&wF[off] = __builtin_bit_cast(uint4v, *(short8*)hi);
            short8 z = {0, 0, 0, 0, 0, 0, 0, 0};
            *(uint4v*)&wF[off + 32768] = __builtin_bit_cast(uint4v, z);
        } else {
            const float* wp = (const float*)w + (size_t)hd * FF * FF;
            float x[8];
#pragma unroll
            for (int j = 0; j < 8; ++j) x[j] = wp[(kb + j) * FF + n];
            uint4v hv = { packhi(x[0], x[1]), packhi(x[2], x[3]),
                          packhi(x[4], x[5]), packhi(x[6], x[7]) };
            uint4v lv = { packhi(x[0] - hitrunc(x[0]), x[1] - hitrunc(x[1])),
                          packhi(x[2] - hitrunc(x[2]), x[3] - hitrunc(x[3])),
                          packhi(x[4] - hitrunc(x[4]), x[5] - hitrunc(x[5])),
                          packhi(x[6] - hitrunc(x[6]), x[7] - hitrunc(x[7])) };
            *(uint4v*)&wF[off] = hv;
            *(uint4v*)&wF[off + 32768] = lv;
        }
    }
}

// ---- Kernel 1: MFMA GEMM hp=h@w; fp32 hp rows + s/d/r per row ---------------
// grid 1024: block = (b, hd, 64-row tile). 256 thr = 4 waves.
__global__ __launch_bounds__(256) void k_proj(
    const void* __restrict__ h, const ushort* __restrict__ wF,
    const void* __restrict__ asrc, const void* __restrict__ adst,
    float* __restrict__ hpF, float* __restrict__ sArr, float* __restrict__ dArr,
    float* __restrict__ rArr)
{
    const int t  = threadIdx.x;
    const int rt = blockIdx.x & 31;
    const int hd = (blockIdx.x >> 5) & 7;
    const int b  = blockIdx.x >> 8;
    const int bh = b * NH + hd;
    const int r0 = rt * 64;

    __shared__ int sb16;
    __shared__ ushort aHi[64 * 64];
    __shared__ ushort aLo[64 * 64];
    __shared__ float  sF[64 * 68];         // fp32 [row][o], stride 68 (bank-safe)
    if (t < 64) {
        int f = sniff_b16(h);
        if (t == 0) sb16 = f;
    }
    __syncthreads();
    const int b16 = sb16;

    const int lane = t & 63, wv = t >> 6;
    const int ml = lane & 15, q = lane >> 4;

    if (b16) {
        const ushort* hsrc = (const ushort*)h + (size_t)(b * NN + r0) * FF;
#pragma unroll
        for (int g0 = 0; g0 < 2; ++g0) {
            int g = t + g0 * 256;
            int row = g >> 3, c8 = (g & 7) * 8;
            uint4v u = *(const uint4v*)(hsrc + row * FF + c8);
            *(uint4v*)&aHi[SWZ(row, c8)] = u;
        }
    } else {
        const float* hsrc = (const float*)h + (size_t)(b * NN + r0) * FF;
#pragma unroll
        for (int g0 = 0; g0 < 4; ++g0) {
            int g = t + g0 * 256;
            int row = g >> 4, c4 = (g & 15) * 4;
            floatx4 x = *(const floatx4*)(hsrc + row * FF + c4);
            uint2 hi2 = { packhi(x[0], x[1]), packhi(x[2], x[3]) };
            uint2 lo2 = { packhi(x[0] - hitrunc(x[0]), x[1] - hitrunc(x[1])),
                          packhi(x[2] - hitrunc(x[2]), x[3] - hitrunc(x[3])) };
            *(uint2*)&aHi[SWZ(row, c4)] = hi2;
            *(uint2*)&aLo[SWZ(row, c4)] = lo2;
        }
    }
    __syncthreads();

    short8 ah[2], al[2];
#pragma unroll
    for (int kc = 0; kc < 2; ++kc) {
        ah[kc] = *(const short8*)&aHi[SWZ(wv * 16 + ml, kc * 32 + q * 8)];
        if (!b16) al[kc] = *(const short8*)&aLo[SWZ(wv * 16 + ml, kc * 32 + q * 8)];
    }
    short8 bhf[4][2], blf[4][2];
    const ushort* wfh = wF + (size_t)hd * 4096;
#pragma unroll
    for (int nt = 0; nt < 4; ++nt)
#pragma unroll
        for (int kc = 0; kc < 2; ++kc) {
            size_t off = ((nt * 2 + kc) * 4 + q) * 128 + ml * 8;
            bhf[nt][kc] = __builtin_bit_cast(short8, *(const uint4v*)&wfh[off]);
            if (!b16) blf[nt][kc] = __builtin_bit_cast(short8, *(const uint4v*)&wfh[off + 32768]);
        }

    float aS[4], aD[4];
#pragma unroll
    for (int nt = 0; nt < 4; ++nt) {
        aS[nt] = LDIN(asrc, hd * FF + nt * 16 + ml, b16);
        aD[nt] = LDIN(adst, hd * FF + nt * 16 + ml, b16);
    }

    floatx4 acc[4];
#pragma unroll
    for (int nt = 0; nt < 4; ++nt) {
        floatx4 a = {0.f, 0.f, 0.f, 0.f};
        if (b16) {
#pragma unroll
            for (int kc = 0; kc < 2; ++kc)
                a = __builtin_amdgcn_mfma_f32_16x16x32_bf16(ah[kc], bhf[nt][kc], a, 0, 0, 0);
        } else {
#pragma unroll
            for (int kc = 0; kc < 2; ++kc) {
                a = __builtin_amdgcn_mfma_f32_16x16x32_bf16(ah[kc], bhf[nt][kc], a, 0, 0, 0);
                a = __builtin_amdgcn_mfma_f32_16x16x32_bf16(ah[kc], blf[nt][kc], a, 0, 0, 0);
                a = __builtin_amdgcn_mfma_f32_16x16x32_bf16(al[kc], bhf[nt][kc], a, 0, 0, 0);
            }
        }
        acc[nt] = a;
    }

    // stage fp32 hp tile [row][o] for coalesced row-major write
#pragma unroll
    for (int nt = 0; nt < 4; ++nt)
#pragma unroll
        for (int reg = 0; reg < 4; ++reg)
            sF[(wv * 16 + q * 4 + reg) * 68 + nt * 16 + ml] = acc[nt][reg];

    float ps[4] = {0.f, 0.f, 0.f, 0.f}, pd[4] = {0.f, 0.f, 0.f, 0.f};
#pragma unroll
    for (int nt = 0; nt < 4; ++nt)
#pragma unroll
        for (int reg = 0; reg < 4; ++reg) {
            float tv = fast_tanh(acc[nt][reg]);
            ps[reg] += tv * aS[nt];
            pd[reg] += tv * aD[nt];
        }
#pragma unroll
    for (int msk = 1; msk < 16; msk <<= 1)
#pragma unroll
        for (int reg = 0; reg < 4; ++reg) {
            ps[reg] += __shfl_xor(ps[reg], msk, 64);
            pd[reg] += __shfl_xor(pd[reg], msk, 64);
        }
    if (ml == 0) {
#pragma unroll
        for (int reg = 0; reg < 4; ++reg) {
            int i = bh * NN + r0 + wv * 16 + q * 4 + reg;
            float sv = ps[reg], dv = pd[reg];
            sArr[i] = sv;
            dArr[i] = dv;
            rArr[i] = __expf(-0.8f * sv);
        }
    }
    __syncthreads();
    {   // coalesced fp32 row write: each thread stores 16 floats of one row
        const int row = t >> 2, cs = (t & 3) * 16;
        const float* sp = &sF[row * 68 + cs];
        float* dst = hpF + ((size_t)bh * NN + r0 + row) * 64 + cs;
        *(floatx4*)(dst)      = *(const floatx4*)(sp);
        *(floatx4*)(dst + 4)  = *(const floatx4*)(sp + 4);
        *(floatx4*)(dst + 8)  = *(const floatx4*)(sp + 8);
        *(floatx4*)(dst + 12) = *(const floatx4*)(sp + 12);
    }
}

// ---- Kernel 2: per-bh sort of d (desc) + chunk totals + prefix/suffix scans -
// grid 32 (one per bh) x 1024 thr (16 waves). Chunks of 32 sorted positions.
// PreR[t][o] = sum_{u<t} exp(d_u) hp_u[o]   (exclusive prefix, t in [0,2048])
// SufR[t][o] = sum_{u>=t} exp(0.2 d_u) hp_u[o]  (inclusive suffix)
__global__ __launch_bounds__(1024) void k_mid(
    const float* __restrict__ dArr, const float* __restrict__ hpF,
    float* __restrict__ SD,
    float* __restrict__ PreR, float* __restrict__ SufR,
    float* __restrict__ PreS, float* __restrict__ SufS)
{
    const int bh = blockIdx.x, t = threadIdx.x;
    const int lane = t & 63, wv = t >> 6;
    __shared__ unsigned long long kp[2048];   // 16 KB
    __shared__ float Teh[64][64];             // 16 KB chunk totals (eh*hp)
    __shared__ float Tel[64][64];             // 16 KB chunk totals (el*hp)
    __shared__ float TehS[64], TelS[64];      // scalar chunk totals

    kp[t]        = packKey(dArr[bh * NN + t], t);
    kp[t + 1024] = packKey(dArr[bh * NN + t + 1024], t + 1024);
    __syncthreads();

    // bitonic ascending on packed key == descending by d
    for (int k = 2; k <= 2048; k <<= 1) {
        for (int j = k >> 1; j > 0; j >>= 1) {
#pragma unroll
            for (int e = 0; e < 2; ++e) {
                int a = t + e * 1024, b = a ^ j;
                if (b > a) {
                    unsigned long long ka = kp[a], kb = kp[b];
                    bool up = ((a & k) == 0);
                    if ((ka > kb) == up) { kp[a] = kb; kp[b] = ka; }
                }
            }
            __syncthreads();
        }
    }

    // sorted d values for k_out's binary search (exact bits)
    SD[bh * NN + t]        = unpackD(kp[t]);
    SD[bh * NN + t + 1024] = unpackD(kp[t + 1024]);

    // chunk totals: wave wv owns chunks 4wv..4wv+3 (32 positions each)
#pragma unroll
    for (int cc = 0; cc < 4; ++cc) {
        int c = wv * 4 + cc;
        float teh = 0.f, tel = 0.f, tehs = 0.f, tels = 0.f;
#pragma unroll 4
        for (int u = 0; u < 32; ++u) {
            unsigned long long kk = kp[c * 32 + u];
            int jj = (int)(kk & 0xFFFFFFFFu);
            float d = unpackD(kk);
            float eh = __expf(d), el = __expf(0.2f * d);
            float hv = hpF[((size_t)bh * NN + jj) * 64 + lane];
            teh += eh * hv; tel += el * hv; tehs += eh; tels += el;
        }
        Teh[c][lane] = teh; Tel[c][lane] = tel;
        if (lane == 0) { TehS[c] = tehs; TelS[c] = tels; }
    }
    __syncthreads();

    // in-place exclusive scans over the chunk axis (one wave each direction)
    if (wv == 0) {
        float rp = 0.f, rps = 0.f;
        for (int c = 0; c < 64; ++c) {
            float tv = Teh[c][lane]; Teh[c][lane] = rp; rp += tv;
            if (lane == 0) { float ts = TehS[c]; TehS[c] = rps; rps += ts; }
        }
        PreR[((size_t)bh * 2049 + 2048) * 64 + lane] = rp;        // grand total
        if (lane == 0) PreS[(size_t)bh * 2049 + 2048] = rps;
    } else if (wv == 1) {
        float rs = 0.f, rss = 0.f;
        for (int c = 63; c >= 0; --c) {
            float tv = Tel[c][lane]; Tel[c][lane] = rs; rs += tv;
            if (lane == 0) { float ts = TelS[c]; TelS[c] = rss; rss += ts; }
        }
        SufR[((size_t)bh * 2049 + 2048) * 64 + lane] = 0.f;       // empty suffix
        if (lane == 0) SufS[(size_t)bh * 2049 + 2048] = 0.f;
    }
    __syncthreads();

    // emit scans (rows are L2-hot from the totals pass)
#pragma unroll
    for (int cc = 0; cc < 4; ++cc) {
        int c = wv * 4 + cc;
        float run = Teh[c][lane];       // exclusive chunk offset
        float runs = TehS[c];
#pragma unroll 4
        for (int u = 0; u < 32; ++u) {
            int x = c * 32 + u;
            unsigned long long kk = kp[x];
            int jj = (int)(kk & 0xFFFFFFFFu);
            PreR[((size_t)bh * 2049 + x) * 64 + lane] = run;
            if (lane == 0) PreS[(size_t)bh * 2049 + x] = runs;
            float eh = __expf(unpackD(kk));
            float hv = hpF[((size_t)bh * NN + jj) * 64 + lane];
            run += eh * hv; runs += eh;
        }
        float runb = Tel[c][lane];      // exclusive chunk suffix offset
        float runbs = TelS[c];
#pragma unroll 4
        for (int u = 31; u >= 0; --u) {
            int x = c * 32 + u;
            unsigned long long kk = kp[x];
            int jj = (int)(kk & 0xFFFFFFFFu);
            float el = __expf(0.2f * unpackD(kk));
            float hv = hpF[((size_t)bh * NN + jj) * 64 + lane];
            runb += el * hv; runbs += el;
            SufR[((size_t)bh * 2049 + x) * 64 + lane] = runb;
            if (lane == 0) SufS[(size_t)bh * 2049 + x] = runbs;
        }
    }
}

// ---- Kernel 3: per-row threshold search + blend + normalize -----------------
// grid 512: block = (bh, 128-row slab), 128 thr = 2 waves, 64 rows/wave.
__global__ __launch_bounds__(128) void k_out(
    const float* __restrict__ SD, const float* __restrict__ sArr,
    const float* __restrict__ rArr,
    const float* __restrict__ PreR, const float* __restrict__ SufR,
    const float* __restrict__ PreS, const float* __restrict__ SufS,
    const void* __restrict__ bias, const int* __restrict__ flag,
    void* __restrict__ out)
{
    const int b16 = flag[0];
    const int t = threadIdx.x;
    const int bh = blockIdx.x >> 4;
    const int i0 = (blockIdx.x & 15) * 128;
    const int wv = t >> 6, lane = t & 63;

    __shared__ float sdL[2048];
    __shared__ int   cntS[128];
    __shared__ float rS[128];
#pragma unroll
    for (int g = 0; g < 4; ++g)
        ((floatx4*)sdL)[t + g * 128] = ((const floatx4*)(SD + bh * NN))[t + g * 128];
    __syncthreads();

    {   // lane-parallel binary search: cnt_i = #{ d_j >= -s_i } (SD descending)
        int i = i0 + wv * 64 + lane;
        float thr = -sArr[bh * NN + i];
        int lo = 0, hi = 2048;
        while (lo < hi) {
            int m = (lo + hi) >> 1;
            if (sdL[m] >= thr) lo = m + 1; else hi = m;
        }
        cntS[wv * 64 + lane] = lo;
        rS[wv * 64 + lane] = rArr[bh * NN + i];
    }
    __syncthreads();

    float biasv = LDIN(bias, lane, b16);
    for (int u = 0; u < 64; ++u) {
        int iu = wv * 64 + u;
        int cnt = cntS[iu];
        float rr = rS[iu];
        size_t ro = ((size_t)bh * 2049 + cnt) * 64 + lane;
        float pre = PreR[ro], suf = SufR[ro];
        float pres = PreS[(size_t)bh * 2049 + cnt];
        float sufs = SufS[(size_t)bh * 2049 + cnt];
        float val = (pre + rr * suf) / (pres + rr * sufs) + biasv;
        size_t oi = ((size_t)bh * NN + i0 + iu) * 64 + lane;
        if (b16) ((__hip_bfloat16*)out)[oi] = __float2bfloat16(val);
        else     ((float*)out)[oi] = val;
    }
}

extern "C" void kernel_launch(void* const* d_in, const int* in_sizes, int n_in,
                              void* d_out, int out_size, void* d_ws, size_t ws_size,
                              hipStream_t stream) {
    const void* h    = d_in[0];
    // d_in[1] = adj (bool) — unused by reference
    const void* w    = d_in[2];
    const void* asrc = d_in[3];
    const void* adst = d_in[4];
    const void* bias = d_in[5];

    float* ws = (float*)d_ws;
    int*    flag = (int*)ws;                          // 16 ints
    float*  hpF  = ws + 16;                           // BH*NN*FF fp32
    float*  sArr = hpF + (size_t)BH * NN * FF;        // BH*NN
    float*  dArr = sArr + BH * NN;
    float*  rArr = dArr + BH * NN;
    float*  SD   = rArr + BH * NN;                    // sorted d, desc
    float*  PreR = SD + BH * NN;                      // BH*2049*FF
    float*  SufR = PreR + (size_t)BH * 2049 * FF;
    float*  PreS = SufR + (size_t)BH * 2049 * FF;     // BH*2049
    float*  SufS = PreS + (size_t)BH * 2049;
    ushort* wF   = (ushort*)(SufS + (size_t)BH * 2049); // 65536 shorts

    k_prep<<<NH, 256, 0, stream>>>(h, w, wF, flag);
    k_proj<<<BDIM * NH * 32, 256, 0, stream>>>(h, wF, asrc, adst,
                                               hpF, sArr, dArr, rArr);
    k_mid<<<BH, 1024, 0, stream>>>(dArr, hpF, SD, PreR, SufR, PreS, SufS);
    k_out<<<BH * 16, 128, 0, stream>>>(SD, sArr, rArr, PreR, SufR, PreS, SufS,
                                       bias, flag, d_out);
}

// Round 2
// 195.304 us; speedup vs baseline: 1.2729x; 1.2729x over previous
//
#include <hip/hip_runtime.h>
#include <hip/hip_bf16.h>

#define NN 2048
#define FF 64
#define NH 8
#define BDIM 4
#define BH 32        // BDIM*NH

typedef __attribute__((ext_vector_type(8))) short short8;
typedef __attribute__((ext_vector_type(4))) float floatx4;
typedef __attribute__((ext_vector_type(4))) unsigned uint4v;
typedef __attribute__((ext_vector_type(2))) unsigned long long u64x2;

__device__ __forceinline__ float LDIN(const void* p, size_t i, int b16) {
    return b16 ? __bfloat162float(((const __hip_bfloat16*)p)[i]) : ((const float*)p)[i];
}
__device__ __forceinline__ unsigned packhi(float f0, float f1) {
    return __builtin_amdgcn_perm(__float_as_uint(f1), __float_as_uint(f0), 0x07060302);
}
__device__ __forceinline__ float hitrunc(float x) {
    return __uint_as_float(__float_as_uint(x) & 0xFFFF0000u);
}
// XOR-swizzled LDS index (stride 64 shorts, 8-short groups). col must be 4-aligned.
__device__ __forceinline__ int SWZ(int row, int col) {
    return row * 64 + ((((col >> 3) ^ (row & 7)) << 3) | (col & 7));
}
__device__ __forceinline__ float fast_tanh(float v) {
    float ex = __expf(2.0f * v);
    return 1.0f - 2.0f * __builtin_amdgcn_rcpf(ex + 1.0f);
}
__device__ __forceinline__ int sniff_b16(const void* h) {
    unsigned word = ((const unsigned*)h)[threadIdx.x & 63];
    unsigned lowexp = (word >> 7) & 0xFFu;
    bool plaus = (lowexp >= 96u && lowexp <= 159u);
    unsigned long long m = __ballot(plaus);
    return (__popcll(m) >= 48) ? 1 : 0;
}
// monotone float->unsigned map: f0 < f1  <=>  mkey(f0) < mkey(f1)
__device__ __forceinline__ unsigned mkey(float f) {
    unsigned u = __float_as_uint(f);
    return (u & 0x80000000u) ? ~u : (u | 0x80000000u);
}
__device__ __forceinline__ float unmkey(unsigned m) {
    unsigned u = (m & 0x80000000u) ? (m - 0x80000000u) : ~m;
    return __uint_as_float(u);
}

// ---- Kernel 0: one-time w fragmentization (unchanged) -----------------------
__global__ __launch_bounds__(256) void k_prep(
    const void* __restrict__ h, const void* __restrict__ w,
    ushort* __restrict__ wF, int* __restrict__ flagOut)
{
    const int hd = blockIdx.x, t = threadIdx.x;
    __shared__ int sb16;
    if (t < 64) {
        int f = sniff_b16(h);
        if (t == 0) { sb16 = f; if (hd == 0) flagOut[0] = f; }
    }
    __syncthreads();
    const int b16 = sb16;

#pragma unroll
    for (int g = 0; g < 2; ++g) {
        int gi = t * 2 + g;
        int ml = gi & 15, q = (gi >> 4) & 3, kc = (gi >> 6) & 1, nt = (gi >> 7) & 3;
        int n = nt * 16 + ml, kb = kc * 32 + q * 8;
        size_t off = (size_t)hd * 4096 + ((nt * 2 + kc) * 4 + q) * 128 + ml * 8;
        if (b16) {
            const ushort* wp = (const ushort*)w + (size_t)hd * FF * FF;
            ushort hi[8];
#pragma unroll
            for (int j = 0; j < 8; ++j) hi[j] = wp[(kb + j) * FF + n];
            *(uint4v*)&wF[off] = __builtin_bit_cast(uint4v, *(short8*)hi);
            short8 z = {0, 0, 0, 0, 0, 0, 0, 0};
            *(uint4v*)&wF[off + 32768] = __builtin_bit_cast(uint4v, z);
        } else {
            const float* wp = (const float*)w + (size_t)hd * FF * FF;
            float x[8];
#pragma unroll
            for (int j = 0; j < 8; ++j) x[j] = wp[(kb + j) * FF + n];
            uint4v hv = { packhi(x[0], x[1]), packhi(x[2], x[3]),
                          packhi(x[4], x[5]), packhi(x[6], x[7]) };
            uint4v lv = { packhi(x[0] - hitrunc(x[0]), x[1] - hitrunc(x[1])),
                          packhi(x[2] - hitrunc(x[2]), x[3] - hitrunc(x[3])),
                          packhi(x[4] - hitrunc(x[4]), x[5] - hitrunc(x[5])),
                          packhi(x[6] - hitrunc(x[6]), x[7] - hitrunc(x[7])) };
            *(uint4v*)&wF[off] = hv;
            *(uint4v*)&wF[off + 32768] = lv;
        }
    }
}

// ---- Kernel 1: MFMA GEMM hp=h@w; fp32 hp rows + s/d/r per row (unchanged) ---
__global__ __launch_bounds__(256) void k_proj(
    const void* __restrict__ h, const ushort* __restrict__ wF,
    const void* __restrict__ asrc, const void* __restrict__ adst,
    float* __restrict__ hpF, float* __restrict__ sArr, float* __restrict__ dArr,
    float* __restrict__ rArr)
{
    const int t  = threadIdx.x;
    const int rt = blockIdx.x & 31;
    const int hd = (blockIdx.x >> 5) & 7;
    const int b  = blockIdx.x >> 8;
    const int bh = b * NH + hd;
    const int r0 = rt * 64;

    __shared__ int sb16;
    __shared__ ushort aHi[64 * 64];
    __shared__ ushort aLo[64 * 64];
    __shared__ float  sF[64 * 68];
    if (t < 64) {
        int f = sniff_b16(h);
        if (t == 0) sb16 = f;
    }
    __syncthreads();
    const int b16 = sb16;

    const int lane = t & 63, wv = t >> 6;
    const int ml = lane & 15, q = lane >> 4;

    if (b16) {
        const ushort* hsrc = (const ushort*)h + (size_t)(b * NN + r0) * FF;
#pragma unroll
        for (int g0 = 0; g0 < 2; ++g0) {
            int g = t + g0 * 256;
            int row = g >> 3, c8 = (g & 7) * 8;
            uint4v u = *(const uint4v*)(hsrc + row * FF + c8);
            *(uint4v*)&aHi[SWZ(row, c8)] = u;
        }
    } else {
        const float* hsrc = (const float*)h + (size_t)(b * NN + r0) * FF;
#pragma unroll
        for (int g0 = 0; g0 < 4; ++g0) {
            int g = t + g0 * 256;
            int row = g >> 4, c4 = (g & 15) * 4;
            floatx4 x = *(const floatx4*)(hsrc + row * FF + c4);
            uint2 hi2 = { packhi(x[0], x[1]), packhi(x[2], x[3]) };
            uint2 lo2 = { packhi(x[0] - hitrunc(x[0]), x[1] - hitrunc(x[1])),
                          packhi(x[2] - hitrunc(x[2]), x[3] - hitrunc(x[3])) };
            *(uint2*)&aHi[SWZ(row, c4)] = hi2;
            *(uint2*)&aLo[SWZ(row, c4)] = lo2;
        }
    }
    __syncthreads();

    short8 ah[2], al[2];
#pragma unroll
    for (int kc = 0; kc < 2; ++kc) {
        ah[kc] = *(const short8*)&aHi[SWZ(wv * 16 + ml, kc * 32 + q * 8)];
        if (!b16) al[kc] = *(const short8*)&aLo[SWZ(wv * 16 + ml, kc * 32 + q * 8)];
    }
    short8 bhf[4][2], blf[4][2];
    const ushort* wfh = wF + (size_t)hd * 4096;
#pragma unroll
    for (int nt = 0; nt < 4; ++nt)
#pragma unroll
        for (int kc = 0; kc < 2; ++kc) {
            size_t off = ((nt * 2 + kc) * 4 + q) * 128 + ml * 8;
            bhf[nt][kc] = __builtin_bit_cast(short8, *(const uint4v*)&wfh[off]);
            if (!b16) blf[nt][kc] = __builtin_bit_cast(short8, *(const uint4v*)&wfh[off + 32768]);
        }

    float aS[4], aD[4];
#pragma unroll
    for (int nt = 0; nt < 4; ++nt) {
        aS[nt] = LDIN(asrc, hd * FF + nt * 16 + ml, b16);
        aD[nt] = LDIN(adst, hd * FF + nt * 16 + ml, b16);
    }

    floatx4 acc[4];
#pragma unroll
    for (int nt = 0; nt < 4; ++nt) {
        floatx4 a = {0.f, 0.f, 0.f, 0.f};
        if (b16) {
#pragma unroll
            for (int kc = 0; kc < 2; ++kc)
                a = __builtin_amdgcn_mfma_f32_16x16x32_bf16(ah[kc], bhf[nt][kc], a, 0, 0, 0);
        } else {
#pragma unroll
            for (int kc = 0; kc < 2; ++kc) {
                a = __builtin_amdgcn_mfma_f32_16x16x32_bf16(ah[kc], bhf[nt][kc], a, 0, 0, 0);
                a = __builtin_amdgcn_mfma_f32_16x16x32_bf16(ah[kc], blf[nt][kc], a, 0, 0, 0);
                a = __builtin_amdgcn_mfma_f32_16x16x32_bf16(al[kc], bhf[nt][kc], a, 0, 0, 0);
            }
        }
        acc[nt] = a;
    }

#pragma unroll
    for (int nt = 0; nt < 4; ++nt)
#pragma unroll
        for (int reg = 0; reg < 4; ++reg)
            sF[(wv * 16 + q * 4 + reg) * 68 + nt * 16 + ml] = acc[nt][reg];

    float ps[4] = {0.f, 0.f, 0.f, 0.f}, pd[4] = {0.f, 0.f, 0.f, 0.f};
#pragma unroll
    for (int nt = 0; nt < 4; ++nt)
#pragma unroll
        for (int reg = 0; reg < 4; ++reg) {
            float tv = fast_tanh(acc[nt][reg]);
            ps[reg] += tv * aS[nt];
            pd[reg] += tv * aD[nt];
        }
#pragma unroll
    for (int msk = 1; msk < 16; msk <<= 1)
#pragma unroll
        for (int reg = 0; reg < 4; ++reg) {
            ps[reg] += __shfl_xor(ps[reg], msk, 64);
            pd[reg] += __shfl_xor(pd[reg], msk, 64);
        }
    if (ml == 0) {
#pragma unroll
        for (int reg = 0; reg < 4; ++reg) {
            int i = bh * NN + r0 + wv * 16 + q * 4 + reg;
            float sv = ps[reg], dv = pd[reg];
            sArr[i] = sv;
            dArr[i] = dv;
            rArr[i] = __expf(-0.8f * sv);
        }
    }
    __syncthreads();
    {
        const int row = t >> 2, cs = (t & 3) * 16;
        const float* sp = &sF[row * 68 + cs];
        float* dst = hpF + ((size_t)bh * NN + r0 + row) * 64 + cs;
        *(floatx4*)(dst)      = *(const floatx4*)(sp);
        *(floatx4*)(dst + 4)  = *(const floatx4*)(sp + 4);
        *(floatx4*)(dst + 8)  = *(const floatx4*)(sp + 8);
        *(floatx4*)(dst + 12) = *(const floatx4*)(sp + 12);
    }
}

// ---- Kernel 2: rank-by-count (replaces bitonic sort; zero inner barriers) ---
// grid 256 = 32 bh x 8 slabs; 256 thr. rank_j = #{K' > K_j} over packed keys
// (descending d, index tie-break). Scatters SDJ[rank] = (mkey(d)<<32)|j.
__global__ __launch_bounds__(256) void k_rank(
    const float* __restrict__ dArr, unsigned long long* __restrict__ SDJ)
{
    const int bh = blockIdx.x >> 3, slab = blockIdx.x & 7, t = threadIdx.x;
    __shared__ __align__(16) unsigned long long kp[2048];
#pragma unroll
    for (int g = 0; g < 8; ++g) {
        int j = t + g * 256;
        unsigned m = mkey(dArr[bh * NN + j]);
        kp[j] = ((unsigned long long)m << 32) | (unsigned)(2047 - j);
    }
    __syncthreads();
    const int j = slab * 256 + t;
    const unsigned long long K = kp[j];
    int cnt = 0;
#pragma unroll 8
    for (int c = 0; c < 2048; c += 4) {
        u64x2 a = *(const u64x2*)&kp[c];
        u64x2 b = *(const u64x2*)&kp[c + 2];
        cnt += (a.x > K) + (a.y > K) + (b.x > K) + (b.y > K);
    }
    unsigned m = (unsigned)(K >> 32);
    SDJ[bh * NN + cnt] = ((unsigned long long)m << 32) | (unsigned)j;
}

// ---- Kernel 3: per-chunk totals (wave = one 32-element chunk) ---------------
// grid 512 = 32 bh x 16; 256 thr = 4 waves.
__global__ __launch_bounds__(256) void k_chunk(
    const unsigned long long* __restrict__ SDJ, const float* __restrict__ hpF,
    float* __restrict__ Teh, float* __restrict__ Tel,
    float* __restrict__ TehS, float* __restrict__ TelS)
{
    const int bh = blockIdx.x >> 4;
    const int c  = (blockIdx.x & 15) * 4 + (threadIdx.x >> 6);
    const int lane = threadIdx.x & 63;
    float teh = 0.f, tel = 0.f, tehs = 0.f, tels = 0.f;
#pragma unroll 4
    for (int u = 0; u < 32; ++u) {
        unsigned long long K = SDJ[bh * NN + c * 32 + u];
        int jj = (int)(K & 0xFFFFFFFFu);
        float d = unmkey((unsigned)(K >> 32));
        float eh = __expf(d), el = __expf(0.2f * d);
        float hv = hpF[((size_t)bh * NN + jj) * 64 + lane];
        teh += eh * hv; tel += el * hv; tehs += eh; tels += el;
    }
    Teh[(bh * 64 + c) * 64 + lane] = teh;
    Tel[(bh * 64 + c) * 64 + lane] = tel;
    if (lane == 0) { TehS[bh * 64 + c] = tehs; TelS[bh * 64 + c] = tels; }
}

// ---- Kernel 4: chunk-axis scans (LDS-preloaded; short dependent chains) -----
// grid 32; 256 thr. CPre[c][o]=sum_{c'<c}Teh; CSufN[c][o]=sum_{c'>c}Tel.
__global__ __launch_bounds__(256) void k_cscan(
    const float* __restrict__ Teh, const float* __restrict__ Tel,
    const float* __restrict__ TehS, const float* __restrict__ TelS,
    float* __restrict__ CPre, float* __restrict__ CSufN,
    float* __restrict__ CPreS, float* __restrict__ CSufNS)
{
    const int bh = blockIdx.x, t = threadIdx.x;
    __shared__ float LA[64 * 64];
    __shared__ float LB[64 * 64];
    __shared__ float LAs[64], LBs[64];
#pragma unroll
    for (int g = 0; g < 16; ++g) {
        LA[t + g * 256] = Teh[bh * 4096 + t + g * 256];
        LB[t + g * 256] = Tel[bh * 4096 + t + g * 256];
    }
    if (t < 64) { LAs[t] = TehS[bh * 64 + t]; LBs[t] = TelS[bh * 64 + t]; }
    __syncthreads();
    const int wv = t >> 6, o = t & 63;
    if (wv == 0) {
        float run = 0.f;
        for (int c = 0; c < 64; ++c) {
            CPre[(bh * 64 + c) * 64 + o] = run;
            run += LA[c * 64 + o];
        }
    } else if (wv == 1) {
        float run = 0.f;
        for (int c = 63; c >= 0; --c) {
            CSufN[(bh * 64 + c) * 64 + o] = run;
            run += LB[c * 64 + o];
        }
    } else if (t == 128) {
        float run = 0.f;
        for (int c = 0; c < 64; ++c) { CPreS[bh * 64 + c] = run; run += LAs[c]; }
    } else if (t == 192) {
        float run = 0.f;
        for (int c = 63; c >= 0; --c) { CSufNS[bh * 64 + c] = run; run += LBs[c]; }
    }
}

// ---- Kernel 5: emit full prefix/suffix tables (wave = chunk, 32 steps) ------
// PreR[x][o] = sum_{rank<x} eh*hp[o] (x in [0,2048]); SufR[x][o] = sum_{rank>=x}.
__global__ __launch_bounds__(256) void k_emit(
    const unsigned long long* __restrict__ SDJ, const float* __restrict__ hpF,
    const float* __restrict__ CPre, const float* __restrict__ CSufN,
    const float* __restrict__ CPreS, const float* __restrict__ CSufNS,
    float* __restrict__ PreR, float* __restrict__ SufR,
    float* __restrict__ PreS, float* __restrict__ SufS)
{
    const int bh = blockIdx.x >> 4;
    const int c  = (blockIdx.x & 15) * 4 + (threadIdx.x >> 6);
    const int lane = threadIdx.x & 63;
    const size_t base = (size_t)bh * 2049;

    float run  = CPre[(bh * 64 + c) * 64 + lane];
    float runs = CPreS[bh * 64 + c];
#pragma unroll 4
    for (int u = 0; u < 32; ++u) {
        int x = c * 32 + u;
        unsigned long long K = SDJ[bh * NN + x];
        int jj = (int)(K & 0xFFFFFFFFu);
        float d = unmkey((unsigned)(K >> 32));
        PreR[(base + x) * 64 + lane] = run;
        if (lane == 0) PreS[base + x] = runs;
        float eh = __expf(d);
        float hv = hpF[((size_t)bh * NN + jj) * 64 + lane];
        run += eh * hv; runs += eh;
    }
    if (c == 63) {
        PreR[(base + 2048) * 64 + lane] = run;
        SufR[(base + 2048) * 64 + lane] = 0.f;
        if (lane == 0) { PreS[base + 2048] = runs; SufS[base + 2048] = 0.f; }
    }

    run  = CSufN[(bh * 64 + c) * 64 + lane];
    runs = CSufNS[bh * 64 + c];
#pragma unroll 4
    for (int u = 31; u >= 0; --u) {
        int x = c * 32 + u;
        unsigned long long K = SDJ[bh * NN + x];
        int jj = (int)(K & 0xFFFFFFFFu);
        float d = unmkey((unsigned)(K >> 32));
        float el = __expf(0.2f * d);
        float hv = hpF[((size_t)bh * NN + jj) * 64 + lane];
        run += el * hv; runs += el;
        SufR[(base + x) * 64 + lane] = run;
        if (lane == 0) SufS[base + x] = runs;
    }
}

// ---- Kernel 6: per-row threshold search + blend + normalize -----------------
// grid 512 = 32 bh x 16 slabs of 128 rows; 256 thr = 4 waves x 32 rows.
__global__ __launch_bounds__(256) void k_out(
    const unsigned long long* __restrict__ SDJ, const float* __restrict__ sArr,
    const float* __restrict__ rArr,
    const float* __restrict__ PreR, const float* __restrict__ SufR,
    const float* __restrict__ PreS, const float* __restrict__ SufS,
    const void* __restrict__ bias, const int* __restrict__ flag,
    void* __restrict__ out)
{
    const int b16 = flag[0];
    const int t = threadIdx.x;
    const int bh = blockIdx.x >> 4;
    const int i0 = (blockIdx.x & 15) * 128;
    const int wv = t >> 6, lane = t & 63;
    __shared__ unsigned sdM[2048];
    __shared__ int   cntS[128];
    __shared__ float rS[128];
#pragma unroll
    for (int g = 0; g < 8; ++g)
        sdM[t + g * 256] = (unsigned)(SDJ[bh * NN + t + g * 256] >> 32);
    __syncthreads();
    if (t < 128) {   // cnt_i = #{ m_j >= m(thr_i) } over descending m array
        int i = i0 + t;
        unsigned mthr = mkey(-sArr[bh * NN + i]);
        int lo = 0, hi = 2048;
        while (lo < hi) {
            int m = (lo + hi) >> 1;
            if (sdM[m] >= mthr) lo = m + 1; else hi = m;
        }
        cntS[t] = lo;
        rS[t] = rArr[bh * NN + i];
    }
    __syncthreads();
    const size_t base = (size_t)bh * 2049;
    float biasv = LDIN(bias, lane, b16);
#pragma unroll 4
    for (int u = 0; u < 32; ++u) {
        int iu = wv * 32 + u;
        int cnt = cntS[iu];
        float rr = rS[iu];
        size_t ro = (base + cnt) * 64 + lane;
        float val = (PreR[ro] + rr * SufR[ro])
                  / (PreS[base + cnt] + rr * SufS[base + cnt]) + biasv;
        size_t oi = ((size_t)bh * NN + i0 + iu) * 64 + lane;
        if (b16) ((__hip_bfloat16*)out)[oi] = __float2bfloat16(val);
        else     ((float*)out)[oi] = val;
    }
}

extern "C" void kernel_launch(void* const* d_in, const int* in_sizes, int n_in,
                              void* d_out, int out_size, void* d_ws, size_t ws_size,
                              hipStream_t stream) {
    const void* h    = d_in[0];
    // d_in[1] = adj (bool) — unused by reference
    const void* w    = d_in[2];
    const void* asrc = d_in[3];
    const void* adst = d_in[4];
    const void* bias = d_in[5];

    float* ws = (float*)d_ws;
    int*    flag = (int*)ws;                              // 16 ints
    float*  hpF  = ws + 16;                               // 32*2048*64 fp32
    float*  sArr = hpF + (size_t)BH * NN * FF;            // 65536
    float*  dArr = sArr + BH * NN;
    float*  rArr = dArr + BH * NN;
    unsigned long long* SDJ = (unsigned long long*)(rArr + BH * NN); // 65536 u64
    float*  Teh  = (float*)(SDJ + (size_t)BH * NN);       // 32*64*64
    float*  Tel  = Teh + BH * 64 * 64;
    float*  TehS = Tel + BH * 64 * 64;                    // 32*64
    float*  TelS = TehS + BH * 64;
    float*  CPre = TelS + BH * 64;                        // 32*64*64
    float*  CSufN = CPre + BH * 64 * 64;
    float*  CPreS = CSufN + BH * 64 * 64;                 // 32*64
    float*  CSufNS = CPreS + BH * 64;
    float*  PreR = CSufNS + BH * 64;                      // 32*2049*64
    float*  SufR = PreR + (size_t)BH * 2049 * FF;
    float*  PreS = SufR + (size_t)BH * 2049 * FF;         // 32*2049
    float*  SufS = PreS + (size_t)BH * 2049;
    ushort* wF   = (ushort*)(SufS + (size_t)BH * 2049);   // 65536 shorts

    k_prep<<<NH, 256, 0, stream>>>(h, w, wF, flag);
    k_proj<<<BDIM * NH * 32, 256, 0, stream>>>(h, wF, asrc, adst,
                                               hpF, sArr, dArr, rArr);
    k_rank<<<BH * 8, 256, 0, stream>>>(dArr, SDJ);
    k_chunk<<<BH * 16, 256, 0, stream>>>(SDJ, hpF, Teh, Tel, TehS, TelS);
    k_cscan<<<BH, 256, 0, stream>>>(Teh, Tel, TehS, TelS,
                                    CPre, CSufN, CPreS, CSufNS);
    k_emit<<<BH * 16, 256, 0, stream>>>(SDJ, hpF, CPre, CSufN, CPreS, CSufNS,
                                        PreR, SufR, PreS, SufS);
    k_out<<<BH * 16, 256, 0, stream>>>(SDJ, sArr, rArr, PreR, SufR, PreS, SufS,
                                       bias, flag, d_out);
}